// Round 7
// baseline (7369.704 us; speedup 1.0000x reference)
//
#include <hip/hip_runtime.h>
#include <stdint.h>

#define BB 64
#define TT 2048
#define EE 256
#define HH 512
#define SLICE 128
#define HXN (BB * 2 * HH)   // u64 exchange slots (512 KiB)

typedef unsigned long long u64;
typedef u64 u64x2 __attribute__((ext_vector_type(2)));
typedef float f32x4 __attribute__((ext_vector_type(4)));

__device__ __forceinline__ u64 pack_vt(float v, unsigned tag) {
    return ((u64)tag << 32) | (u64)__float_as_uint(v);
}
// plain 16B store: write-through L1, lands in this XCD's write-back L2
__device__ __forceinline__ void st_l2_x4(u64* p, u64x2 v) {
    asm volatile("global_store_dwordx4 %0, %1, off" :: "v"((u64)p), "v"(v) : "memory");
}
// sc0 16B load: bypasses L1, reads the shared XCD L2
__device__ __forceinline__ u64x2 ld_l2_x4(const u64* p) {
    u64x2 v;
    asm volatile("global_load_dwordx4 %0, %1, off sc0\n\ts_waitcnt vmcnt(0)"
                 : "=v"(v) : "v"((u64)p) : "memory");
    return v;
}
// barrier with LDS-only drain: does NOT wait for in-flight global stores
__device__ __forceinline__ void barrier_lds(void) {
    asm volatile("s_waitcnt lgkmcnt(0)\n\ts_barrier" ::: "memory");
}

#define AGENT __HIP_MEMORY_SCOPE_AGENT
__device__ __forceinline__ unsigned a_add(unsigned* p, unsigned v, int mo) {
    return __hip_atomic_fetch_add(p, v, mo, AGENT);
}

// 256 blocks x 256 threads (4 waves = 1/SIMD, 512-reg unified budget).
// Compute core identical to round 6 (proven: 256 VGPR + 256 AGPR, no spill).
// NEW: blocks claim (batch, slice) via per-XCD pools read from HW_REG_XCC_ID,
// so a batch's 4 blocks share an XCD L2 -> exchange via plain store + sc0 load
// (~200cy) instead of agent atomics through L3/HBM (~2us). Agent path kept as
// dual-publish + bounded-fallback safety net; barrier no longer drains vmcnt.
__global__ __attribute__((amdgpu_flat_work_group_size(256, 256),
                          amdgpu_waves_per_eu(1, 1)))
void rnn_scan(const float* __restrict__ x,
              const int* __restrict__ lengths,
              const float* __restrict__ W_ih,
              const float* __restrict__ W_hh,
              const float* __restrict__ b_ih,
              const float* __restrict__ b_hh,
              const float* __restrict__ w_fc,
              const float* __restrict__ b_fc,
              float* __restrict__ out,   // [64] counts ++ [64][512] h_n
              u64* __restrict__ hx)      // [HXN] exchange ++ boot counters
{
    const int tid = threadIdx.x;
    const int rg  = tid >> 3;      // 0..31 (4 rows each)
    const int kg  = tid & 7;       // 0..7  (64-wide k slice)

    __shared__ float lds_h[2][HH];
    __shared__ float lds_x[2][EE];
    __shared__ float lds_wf[HH];
    __shared__ int sh_batch, sh_slice, sh_fast, sh_miss;

    // ---- bootstrap: claim (batch, slice) from this XCD's pool ----
    if (tid == 0) {
        unsigned xcd;
        asm volatile("s_getreg_b32 %0, hwreg(HW_REG_XCC_ID)" : "=s"(xcd));
        xcd &= 7u;
        unsigned* boot = (unsigned*)(hx + HXN);
        unsigned* cnt   = boot;        // [8] per-XCD claim counters
        unsigned* total = boot + 8;    // grid rendezvous
        unsigned* ovfc  = boot + 9;    // overflow pool counter
        unsigned* bp1   = boot + 16;   // [64] phase-1 claims per batch
        unsigned* clm   = boot + 80;   // [256] claimed bitmap per slot
        unsigned my = a_add(&cnt[xcd], 1u, __ATOMIC_RELAXED);
        int batch = -1, slice = 0, p1 = 0;
        if (my < 32u) {
            unsigned slot = xcd * 32u + my;   // slot == batch*4 + slice
            batch = (int)(slot >> 2); slice = (int)(slot & 3u); p1 = 1;
            __hip_atomic_store(&clm[slot], 1u, __ATOMIC_RELAXED, AGENT);
            a_add(&bp1[batch], 1u, __ATOMIC_RELAXED);
        }
        a_add(total, 1u, __ATOMIC_RELEASE);
        int g = 0;
        while (__hip_atomic_load(total, __ATOMIC_ACQUIRE, AGENT) < 256u &&
               ++g < (1 << 26)) {}
        if (!p1) {   // take k-th unclaimed slot (agent protocol)
            unsigned k = a_add(ovfc, 1u, __ATOMIC_RELAXED);
            unsigned seen = 0, slot = 0;
            for (unsigned i2 = 0; i2 < 256u; ++i2) {
                if (!__hip_atomic_load(&clm[i2], __ATOMIC_RELAXED, AGENT)) {
                    if (seen == k) { slot = i2; break; }
                    ++seen;
                }
            }
            batch = (int)(slot >> 2); slice = (int)(slot & 3u);
        }
        const int fast =
            (__hip_atomic_load(&bp1[batch], __ATOMIC_RELAXED, AGENT) == 4u);
        sh_batch = batch; sh_slice = slice; sh_fast = fast; sh_miss = 0;
    }
    __syncthreads();
    const int b = sh_batch, s = sh_slice;
    bool fastp = (sh_fast != 0);
    const int row0 = s * SLICE + rg * 4;

    // ---- W_hh into AGPRs, W_ih into VGPRs (pre-permuted, pinned) ----
    f32x4 whh[4][16];
#pragma unroll
    for (int j = 0; j < 4; ++j)
#pragma unroll
        for (int i = 0; i < 16; ++i) {
            const int q = (i + kg) & 15;
            whh[j][i] = *(const f32x4*)&W_hh[(size_t)(row0 + j) * HH + kg * 64 + q * 4];
            asm volatile("" : "+a"(whh[j][i]));
        }
    f32x4 wih[4][8];
#pragma unroll
    for (int j = 0; j < 4; ++j)
#pragma unroll
        for (int i = 0; i < 8; ++i) {
            const int q = (i + kg) & 7;
            wih[j][i] = *(const f32x4*)&W_ih[(size_t)(row0 + j) * EE + kg * 32 + q * 4];
            asm volatile("" : "+v"(wih[j][i]));
        }
    const int pr0 = row0 + (kg & 1) * 2;          // producer rows (kg<2 lanes)
    const float bs0 = b_ih[pr0] + b_hh[pr0];
    const float bs1 = b_ih[pr0 + 1] + b_hh[pr0 + 1];
    float bfc = 0.f;
    if (s == 0 && tid < 64) bfc = b_fc[0];
    lds_wf[tid]       = w_fc[tid];
    lds_wf[tid + 256] = w_fc[tid + 256];

    const int len = lengths[b];
    const float* xrow = x + (size_t)b * TT * EE;
    u64* hxb = hx + (size_t)b * 2 * HH;   // [2][512] parity slots

    lds_h[0][tid]       = 0.f;
    lds_h[0][tid + 256] = 0.f;
    if (tid < 64) *(f32x4*)&lds_x[0][tid * 4] = *(const f32x4*)&xrow[tid * 4];
    __syncthreads();

    int count = 0;

#pragma unroll 1
    for (int t = 0; t < len; ++t) {
        const int p = t & 1;
        const int si = tid - 192;   // stagers: tid in [192,256)
        f32x4 xn = {0.f, 0.f, 0.f, 0.f};
        if (si >= 0 && t + 1 < TT)
            xn = *(const f32x4*)&xrow[(size_t)(t + 1) * EE + si * 4];

        // ---- register-blocked GEMV: 4 rows x (64 hk + 32 xe), rotated reads ----
        const float* hb = &lds_h[p][kg * 64];
        const float* xb = &lds_x[p][kg * 32];
        f32x4 a0 = {0.f,0.f,0.f,0.f}, a1 = a0, a2 = a0, a3 = a0;
#define FMA4(acc, w, v) \
        acc[0] = fmaf((w)[0], (v)[0], acc[0]); acc[1] = fmaf((w)[1], (v)[1], acc[1]); \
        acc[2] = fmaf((w)[2], (v)[2], acc[2]); acc[3] = fmaf((w)[3], (v)[3], acc[3]);
#pragma unroll
        for (int i = 0; i < 16; ++i) {
            f32x4 hv = *(const f32x4*)(hb + ((i + kg) & 15) * 4);
            FMA4(a0, whh[0][i], hv) FMA4(a1, whh[1][i], hv)
            FMA4(a2, whh[2][i], hv) FMA4(a3, whh[3][i], hv)
        }
#pragma unroll
        for (int i = 0; i < 8; ++i) {
            f32x4 xv = *(const f32x4*)(xb + ((i + kg) & 7) * 4);
            FMA4(a0, wih[0][i], xv) FMA4(a1, wih[1][i], xv)
            FMA4(a2, wih[2][i], xv) FMA4(a3, wih[3][i], xv)
        }
        float r0 = (a0[0] + a0[1]) + (a0[2] + a0[3]);
        float r1 = (a1[0] + a1[1]) + (a1[2] + a1[3]);
        float r2 = (a2[0] + a2[1]) + (a2[2] + a2[3]);
        float r3 = (a3[0] + a3[1]) + (a3[2] + a3[3]);
#pragma unroll
        for (int m = 1; m < 8; m <<= 1) {          // butterfly over 8 kg lanes
            r0 += __shfl_xor(r0, m); r1 += __shfl_xor(r1, m);
            r2 += __shfl_xor(r2, m); r3 += __shfl_xor(r3, m);
        }

        const unsigned tag = (unsigned)(t + 1);
        u64* slot = hxb + (size_t)p * HH;

        if (kg < 2) {   // producers: 2 rows each -> 128 h values per block
            const float h0 = tanhf((kg ? r2 : r0) + bs0);
            const float h1 = tanhf((kg ? r3 : r1) + bs1);
            const int gi = pr0;   // even -> 16B aligned slot pair
            *(float2*)&lds_h[p ^ 1][gi] = make_float2(h0, h1);
            const u64 q0 = pack_vt(h0, tag), q1 = pack_vt(h1, tag);
            u64x2 q; q[0] = q0; q[1] = q1;
            st_l2_x4(&slot[gi], q);   // fast path (same-XCD L2)
            __hip_atomic_store(&slot[gi], q0, __ATOMIC_RELAXED, AGENT);
            __hip_atomic_store(&slot[gi + 1], q1, __ATOMIC_RELAXED, AGENT);
        }

        if (tid < 192) {   // pollers: 3 remote slices, 2 values each
            const int sp = (s + 1 + (tid >> 6)) & 3;
            const int gi = sp * SLICE + (tid & 63) * 2;
            u64 v0 = 0, v1 = 0;
            bool ok = false;
            if (fastp) {
                for (int g = 0; g < 256; ++g) {
                    u64x2 v = ld_l2_x4(&slot[gi]);
                    if ((unsigned)(v[0] >> 32) == tag &&
                        (unsigned)(v[1] >> 32) == tag) {
                        v0 = v[0]; v1 = v[1]; ok = true; break;
                    }
                }
                if (!ok) atomicAdd(&sh_miss, 1);
            }
            if (!ok) {   // proven agent fallback
                int g = 0;
                do { v0 = __hip_atomic_load(&slot[gi], __ATOMIC_RELAXED, AGENT);
                } while ((unsigned)(v0 >> 32) != tag && ++g < (1 << 22));
                g = 0;
                do { v1 = __hip_atomic_load(&slot[gi + 1], __ATOMIC_RELAXED, AGENT);
                } while ((unsigned)(v1 >> 32) != tag && ++g < (1 << 22));
            }
            *(float2*)&lds_h[p ^ 1][gi] =
                make_float2(__uint_as_float((unsigned)v0),
                            __uint_as_float((unsigned)v1));
        } else if (t + 1 < TT) {   // stagers: commit prefetched x row
            *(f32x4*)&lds_x[p ^ 1][si * 4] = xn;
        }
        barrier_lds();   // h_t complete in lds_h[p^1]; no vmcnt drain

        if (fastp && sh_miss >= 4) fastp = false;   // sticky self-demotion

        if (s == 0) {
            if (tid < 64) {   // fc logit count (wave 0)
                const f32x4* h4  = (const f32x4*)lds_h[p ^ 1];
                const f32x4* wf4 = (const f32x4*)lds_wf;
                f32x4 v0 = h4[tid * 2], v1 = h4[tid * 2 + 1];
                f32x4 w0 = wf4[tid * 2], w1 = wf4[tid * 2 + 1];
                float pd = v0[0]*w0[0] + v0[1]*w0[1] + v0[2]*w0[2] + v0[3]*w0[3]
                         + v1[0]*w1[0] + v1[1]*w1[1] + v1[2]*w1[2] + v1[3]*w1[3];
#pragma unroll
                for (int m = 1; m < 64; m <<= 1) pd += __shfl_xor(pd, m);
                if (tid == 0 && (pd + bfc) > 0.f) count++;
            }
            if (t == len - 1) {
                *(float2*)&out[64 + b * HH + tid * 2] =
                    *(const float2*)&lds_h[p ^ 1][tid * 2];
            }
        }
    }

    if (s == 0 && tid == 0) out[b] = (float)count;
}

extern "C" void kernel_launch(void* const* d_in, const int* in_sizes, int n_in,
                              void* d_out, int out_size, void* d_ws, size_t ws_size,
                              hipStream_t stream) {
    const float* x       = (const float*)d_in[0];
    const int*   lengths = (const int*)  d_in[1];
    const float* W_ih    = (const float*)d_in[2];
    const float* W_hh    = (const float*)d_in[3];
    const float* b_ih    = (const float*)d_in[4];
    const float* b_hh    = (const float*)d_in[5];
    const float* w_fc    = (const float*)d_in[6];
    const float* b_fc    = (const float*)d_in[7];
    float* out = (float*)d_out;
    u64*   hx  = (u64*)d_ws;   // 512KB exchange + 2KB bootstrap counters

    // zero the bootstrap counter region (exchange tags are poison-safe: 0xAA..
    // high words never match a step tag <= 2048)
    hipMemsetAsync((char*)d_ws + (size_t)HXN * 8, 0, 2048, stream);
    hipLaunchKernelGGL(rnn_scan, dim3(BB * 4), dim3(256), 0, stream,
                       x, lengths, W_ih, W_hh, b_ih, b_hh, w_fc, b_fc, out, hx);
}